// Round 15
// baseline (198.593 us; speedup 1.0000x reference)
//
#include <hip/hip_runtime.h>

// SSIM loss, fused separable Gaussian (11x11, sigma=1.5) over [32,3,512,512] f32.
// R15 = R11 skeleton (sea of independent one-tile blocks, plain store + reduce
// kernel) + column-pair vectorization on full-width tiles:
//  - tile = 4 rows x 512 cols (no wt split), 12288 blocks, XCD-bijective
//    swizzle with ht-contiguity (keeps FETCH ~100 MB).
//  - V-phase thread owns an EVEN col pair (2k-6, 2k-5): 28 dwordx2 loads
//    (half the loads+addressing of R11), and since [0,511] is even-aligned,
//    every pair is fully-interior or fully-zero -> NO per-element masks or
//    clamps in the hot path (dead pairs write zeros; border rows = uniform
//    branch at ht==0/127 only).
//  - stats LDS written as b128 (2 cols x f32x2 chain-pair), H-phase reads
//    8 outputs/thread via 20 b128 (2.5/output vs R11's 7).
//  - R14's persistent-slab experiment regressed (occupancy 22%) -> reverted.

typedef float f32x2 __attribute__((ext_vector_type(2)));

#define IH 512
#define IW 512
#define TH 4                 // output rows per tile
#define NPAIR 262            // col pairs covering padded width -6..517
#define PSTART 3             // first fully-valid pair (cols 0,1)
#define PEND 258             // last fully-valid pair (cols 510,511)
#define LPW 524              // stats row stride in f32x2 (col c at idx c+6)
#define HTILES 128
#define NBLK 12288           // 96 images * 128 ht
#define CPX 1536             // NBLK / 8 XCDs (exact -> bijective)
#define NPIX 25165824.0f     // 96*512*512
#define NTHR 320

constexpr float GW[11] = {
    0.00102838f, 0.00759877f, 0.03600078f, 0.10936070f, 0.21300554f,
    0.26601173f,
    0.21300554f, 0.10936070f, 0.03600078f, 0.00759877f, 0.00102838f
};
constexpr float C1f = 0.0001f;  // 0.01^2
constexpr float C2f = 0.0009f;  // 0.03^2

__global__ __launch_bounds__(1024) void ssim_reduce(
    const float* __restrict__ ws, float* __restrict__ out)
{
    __shared__ float wsum[16];
    const int tid = threadIdx.x;
    const float4* w4 = reinterpret_cast<const float4*>(ws);  // 3072 float4
    float s = 0.0f;
    #pragma unroll
    for (int i = 0; i < 3; ++i) {
        const float4 v = w4[tid + i * 1024];
        s += (v.x + v.y) + (v.z + v.w);
    }
    #pragma unroll
    for (int off = 32; off > 0; off >>= 1) s += __shfl_down(s, off, 64);
    if ((tid & 63) == 0) wsum[tid >> 6] = s;
    __syncthreads();
    if (tid == 0) {
        float t = 0.f;
        #pragma unroll
        for (int i = 0; i < 16; ++i) t += wsum[i];
        out[0] = 1.0f - t * (1.0f / NPIX);
    }
}

__global__ __launch_bounds__(NTHR, 4) void ssim_main(
    const float* __restrict__ pred,
    const float* __restrict__ targ,
    float* __restrict__ ws)
{
    __shared__ __align__(16) f32x2 lds01[TH][LPW];   // (E[p], E[t])
    __shared__ __align__(16) f32x2 lds23[TH][LPW];   // (E[p^2+t^2], E[p*t])
    __shared__ float wsum[5];

    const int tid = threadIdx.x;

    // -------- XCD-bijective swizzle: ht-consecutive tiles share an XCD -----
    const int b  = blockIdx.x;
    const int tl = (b & 7) * CPX + (b >> 3);
    const int ht = tl & (HTILES - 1);
    const int bc = tl >> 7;

    const int rbase = ht * TH - 5;
    const bool border = (ht == 0) || (ht == HTILES - 1);   // uniform
    const float* __restrict__ P = pred + (size_t)bc * (IH * IW);
    const float* __restrict__ T = targ + (size_t)bc * (IH * IW);

    // ---------------- V-phase: column-pair FIR -----------------------------
    if (tid < NPAIR) {
        const bool hot = (tid >= PSTART) && (tid <= PEND);
        if (hot) {
            const int wA = 2 * tid - 6;          // even, in [0, 510]
            f32x2 pv[14], tv[14];
            #pragma unroll
            for (int rr = 0; rr < 14; ++rr) {
                const int h = rbase + rr;
                const int hc = h < 0 ? 0 : (h > IH - 1 ? IH - 1 : h);
                pv[rr] = *reinterpret_cast<const f32x2*>(P + (size_t)hc * IW + wA);
                tv[rr] = *reinterpret_cast<const f32x2*>(T + (size_t)hc * IW + wA);
            }
            __builtin_amdgcn_sched_barrier(0);   // batch all 28 before use

            f32x2 aA01[TH], aB01[TH], aA23[TH], aB23[TH];
            #pragma unroll
            for (int ro = 0; ro < TH; ++ro) {
                aA01[ro] = (f32x2){0.f, 0.f}; aB01[ro] = (f32x2){0.f, 0.f};
                aA23[ro] = (f32x2){0.f, 0.f}; aB23[ro] = (f32x2){0.f, 0.f};
            }
            #pragma unroll
            for (int rr = 0; rr < 14; ++rr) {
                float pA = pv[rr].x, pB = pv[rr].y;
                float tA = tv[rr].x, tB = tv[rr].y;
                if (border) {                     // uniform branch
                    const float rmk =
                        ((unsigned)(rbase + rr) < (unsigned)IH) ? 1.0f : 0.0f;
                    pA *= rmk; pB *= rmk; tA *= rmk; tB *= rmk;
                }
                const f32x2 sA01 = {pA, tA};
                const f32x2 sB01 = {pB, tB};
                const f32x2 sA23 = {fmaf(pA, pA, tA * tA), pA * tA};
                const f32x2 sB23 = {fmaf(pB, pB, tB * tB), pB * tB};
                #pragma unroll
                for (int ro = 0; ro < TH; ++ro) {
                    const int k = rr - ro;        // static after unroll
                    if (k >= 0 && k < 11) {
                        const f32x2 g = {GW[k], GW[k]};
                        aA01[ro] = __builtin_elementwise_fma(g, sA01, aA01[ro]);
                        aB01[ro] = __builtin_elementwise_fma(g, sB01, aB01[ro]);
                        aA23[ro] = __builtin_elementwise_fma(g, sA23, aA23[ro]);
                        aB23[ro] = __builtin_elementwise_fma(g, sB23, aB23[ro]);
                    }
                }
            }
            #pragma unroll
            for (int ro = 0; ro < TH; ++ro) {
                float4 u; u.x = aA01[ro].x; u.y = aA01[ro].y;
                          u.z = aB01[ro].x; u.w = aB01[ro].y;
                float4 v; v.x = aA23[ro].x; v.y = aA23[ro].y;
                          v.z = aB23[ro].x; v.w = aB23[ro].y;
                *reinterpret_cast<float4*>(&lds01[ro][2 * tid]) = u;
                *reinterpret_cast<float4*>(&lds23[ro][2 * tid]) = v;
            }
        } else {
            const float4 z = {0.f, 0.f, 0.f, 0.f};
            #pragma unroll
            for (int ro = 0; ro < TH; ++ro) {
                *reinterpret_cast<float4*>(&lds01[ro][2 * tid]) = z;
                *reinterpret_cast<float4*>(&lds23[ro][2 * tid]) = z;
            }
        }
    }
    __syncthreads();

    // ---------------- H-phase: 8 outputs/thread + SSIM epilogue ------------
    float lsum = 0.0f;
    if (tid < 256) {
        const int r  = tid >> 6;             // wave-uniform row 0..3
        const int c0 = (tid & 63) << 3;      // output col block, 0..504

        // stats idx window c0 .. c0+19 (taps for outputs c0..c0+7 are
        // idx c0+j+1 .. c0+j+11) -> 10 b128 per chain-pair
        float4 u4[10], v4[10];
        const float4* b01 = reinterpret_cast<const float4*>(&lds01[r][c0]);
        const float4* b23 = reinterpret_cast<const float4*>(&lds23[r][c0]);
        #pragma unroll
        for (int q = 0; q < 10; ++q) { u4[q] = b01[q]; v4[q] = b23[q]; }
        const f32x2* x01 = reinterpret_cast<const f32x2*>(u4);   // 20 elems
        const f32x2* x23 = reinterpret_cast<const f32x2*>(v4);

        #pragma unroll
        for (int j = 0; j < 8; ++j) {
            f32x2 acc01 = {0.f, 0.f};
            f32x2 acc23 = {0.f, 0.f};
            #pragma unroll
            for (int k = 0; k < 11; ++k) {
                const f32x2 g = {GW[k], GW[k]};
                acc01 = __builtin_elementwise_fma(g, x01[j + k + 1], acc01);
                acc23 = __builtin_elementwise_fma(g, x23[j + k + 1], acc23);
            }
            const float m1  = acc01.x;
            const float m2  = acc01.y;
            const float sPP = acc23.x;      // E[p^2]+E[t^2]
            const float e12 = acc23.y;      // E[p*t]
            const float m1m2 = m1 * m2;
            const float msq  = fmaf(m1, m1, m2 * m2);
            const float num = fmaf(2.0f, m1m2, C1f) * fmaf(2.0f, (e12 - m1m2), C2f);
            const float den = (msq + C1f) * ((sPP - msq) + C2f);
            lsum = fmaf(num, __builtin_amdgcn_rcpf(den), lsum);
        }
    }

    // ---------------- Reduction: wave shuffle -> LDS -> plain store --------
    #pragma unroll
    for (int off = 32; off > 0; off >>= 1) lsum += __shfl_down(lsum, off, 64);
    const int lane = tid & 63;
    const int wv   = tid >> 6;              // 0..4
    if (lane == 0) wsum[wv] = lsum;
    __syncthreads();
    if (tid == 0) {
        ws[b] = wsum[0] + wsum[1] + wsum[2] + wsum[3] + wsum[4];
    }
}

extern "C" void kernel_launch(void* const* d_in, const int* in_sizes, int n_in,
                              void* d_out, int out_size, void* d_ws, size_t ws_size,
                              hipStream_t stream) {
    const float* pred = (const float*)d_in[0];
    const float* targ = (const float*)d_in[1];
    float* out = (float*)d_out;
    float* wsf = (float*)d_ws;               // needs 12288 floats = 48 KB

    hipLaunchKernelGGL(ssim_main, dim3(NBLK), dim3(NTHR), 0, stream,
                       pred, targ, wsf);
    hipLaunchKernelGGL(ssim_reduce, dim3(1), dim3(1024), 0, stream, wsf, out);
}

// Round 16
// 85.969 us; speedup vs baseline: 2.3101x; 2.3101x over previous
//
#include <hip/hip_runtime.h>

// SSIM loss, fused separable Gaussian (11x11, sigma=1.5) over [32,3,512,512] f32.
// R16 = R11 skeleton (independent one-tile blocks, R11's exact LDS geometry,
// plain store + reduce kernel) with TH 4 -> 8:
//  - tile = 8 rows x 256 cols; 12288 blocks; 18 raw rows per column serve 8
//    output rows: vertical load+addr amplification 3.5x -> 2.25x, per-output
//    V setup -35%. FIR math per output unchanged (essential).
//  - border handling is a UNIFORM branch taken only at ht==0/63; interior
//    tiles (62/64) run zero masks, zero clamps.
//  - H-phase identical per-output geometry to R11 (32B lane stride, known
//    ~4-way conflict) run twice (rows r and r+4). R15's 64B-stride read
//    layout (49.5M conflicts) reverted.
//  - LDS 34.4 KB -> 4 blocks/CU ceiling; accepted trade vs -27% instructions.

typedef float f32x2 __attribute__((ext_vector_type(2)));

#define IH 512
#define IW 512
#define TH 8                 // output rows per tile
#define TW 256               // output cols per tile
#define PW 266               // TW + 10 FIR cols
#define RRN 18               // raw rows per tile
#define LPW 268              // stats row stride in f32x2
#define HTILES 64
#define NBLK 12288           // 96 images * 64 ht * 2 wt
#define CPX 1536             // NBLK / 8 XCDs (exact -> bijective)
#define NPIX 25165824.0f     // 96*512*512
#define NTHR 320

constexpr float GW[11] = {
    0.00102838f, 0.00759877f, 0.03600078f, 0.10936070f, 0.21300554f,
    0.26601173f,
    0.21300554f, 0.10936070f, 0.03600078f, 0.00759877f, 0.00102838f
};
constexpr float C1f = 0.0001f;  // 0.01^2
constexpr float C2f = 0.0009f;  // 0.03^2

__global__ __launch_bounds__(1024) void ssim_reduce(
    const float* __restrict__ ws, float* __restrict__ out)
{
    __shared__ float wsum[16];
    const int tid = threadIdx.x;
    const float4* w4 = reinterpret_cast<const float4*>(ws);  // 3072 float4
    float s = 0.0f;
    #pragma unroll
    for (int i = 0; i < 3; ++i) {
        const float4 v = w4[tid + i * 1024];
        s += (v.x + v.y) + (v.z + v.w);
    }
    #pragma unroll
    for (int off = 32; off > 0; off >>= 1) s += __shfl_down(s, off, 64);
    if ((tid & 63) == 0) wsum[tid >> 6] = s;
    __syncthreads();
    if (tid == 0) {
        float t = 0.f;
        #pragma unroll
        for (int i = 0; i < 16; ++i) t += wsum[i];
        out[0] = 1.0f - t * (1.0f / NPIX);
    }
}

__global__ __launch_bounds__(NTHR, 2) void ssim_main(
    const float* __restrict__ pred,
    const float* __restrict__ targ,
    float* __restrict__ ws)
{
    __shared__ __align__(16) f32x2 lds01[TH][LPW];   // (E[p], E[t])
    __shared__ __align__(16) f32x2 lds23[TH][LPW];   // (E[p^2+t^2], E[p*t])
    __shared__ float wsum[5];

    const int tid = threadIdx.x;

    // -------- XCD-bijective swizzle: tl-consecutive tiles share an XCD -----
    const int b  = blockIdx.x;
    const int tl = (b & 7) * CPX + (b >> 3);
    const int ht = tl & (HTILES - 1);            // consecutive ht share rows
    const int wt = (tl >> 6) & 1;
    const int bc = tl >> 7;

    const int rbase = ht * TH - 5;
    const bool vint = (ht != 0) && (ht != HTILES - 1);   // uniform
    const float* __restrict__ P = pred + (size_t)bc * (IH * IW);
    const float* __restrict__ T = targ + (size_t)bc * (IH * IW);

    // ---------------- V-phase: 18-row column FIR ---------------------------
    if (tid < PW) {
        const int w = wt * TW - 5 + tid;
        const float wm = ((unsigned)w < (unsigned)IW) ? 1.0f : 0.0f;
        const int wc = w < 0 ? 0 : (w > IW - 1 ? IW - 1 : w);

        float pv[RRN], tv[RRN];
        if (vint) {
            // interior: no clamps, no masks
            const float* __restrict__ Pp = P + (size_t)rbase * IW + wc;
            const float* __restrict__ Tp = T + (size_t)rbase * IW + wc;
            #pragma unroll
            for (int rr = 0; rr < RRN; ++rr) pv[rr] = Pp[(size_t)rr * IW];
            #pragma unroll
            for (int rr = 0; rr < RRN; ++rr) tv[rr] = Tp[(size_t)rr * IW];
        } else {
            // border: clamp rows + zero masks
            #pragma unroll
            for (int rr = 0; rr < RRN; ++rr) {
                const int h = rbase + rr;
                const int hc = h < 0 ? 0 : (h > IH - 1 ? IH - 1 : h);
                const float rmk = ((unsigned)h < (unsigned)IH) ? 1.0f : 0.0f;
                pv[rr] = P[(size_t)hc * IW + wc] * rmk;
                tv[rr] = T[(size_t)hc * IW + wc] * rmk;
            }
        }
        __builtin_amdgcn_sched_barrier(0);   // batch loads before FIR

        f32x2 a01[TH], a23[TH];
        #pragma unroll
        for (int ro = 0; ro < TH; ++ro) {
            a01[ro] = (f32x2){0.f, 0.f};
            a23[ro] = (f32x2){0.f, 0.f};
        }

        #pragma unroll
        for (int rr = 0; rr < RRN; ++rr) {
            const float p = pv[rr], t = tv[rr];
            f32x2 s01; s01.x = p; s01.y = t;
            f32x2 s23;
            s23.x = fmaf(p, p, t * t);        // p^2 + t^2
            s23.y = p * t;                    // p*t
            #pragma unroll
            for (int ro = 0; ro < TH; ++ro) {
                const int k = rr - ro;        // static after unroll
                if (k >= 0 && k < 11) {
                    const f32x2 g = {GW[k], GW[k]};
                    a01[ro] = __builtin_elementwise_fma(g, s01, a01[ro]);
                    a23[ro] = __builtin_elementwise_fma(g, s23, a23[ro]);
                }
            }
        }
        const f32x2 wmv = {wm, wm};
        #pragma unroll
        for (int ro = 0; ro < TH; ++ro) {
            lds01[ro][tid] = a01[ro] * wmv;
            lds23[ro][tid] = a23[ro] * wmv;
        }
    }
    __syncthreads();

    // ---------------- H-phase: two row-quads + SSIM epilogue ---------------
    float lsum = 0.0f;
    if (tid < 256) {
        const int c0 = (tid & 63) << 2;     // 0..252 (f32x2 elements)
        #pragma unroll
        for (int half = 0; half < 2; ++half) {
            const int r = (tid >> 6) + half * 4;   // rows 0..3 then 4..7

            float4 u4[7], v4[7];
            const float4* b01 = reinterpret_cast<const float4*>(&lds01[r][c0]);
            const float4* b23 = reinterpret_cast<const float4*>(&lds23[r][c0]);
            #pragma unroll
            for (int q = 0; q < 7; ++q) { u4[q] = b01[q]; v4[q] = b23[q]; }
            const f32x2* x01 = reinterpret_cast<const f32x2*>(u4);   // 14
            const f32x2* x23 = reinterpret_cast<const f32x2*>(v4);

            #pragma unroll
            for (int j = 0; j < 4; ++j) {
                f32x2 acc01 = {0.f, 0.f};
                f32x2 acc23 = {0.f, 0.f};
                #pragma unroll
                for (int k = 0; k < 11; ++k) {
                    const f32x2 g = {GW[k], GW[k]};
                    acc01 = __builtin_elementwise_fma(g, x01[j + k], acc01);
                    acc23 = __builtin_elementwise_fma(g, x23[j + k], acc23);
                }
                const float m1  = acc01.x;
                const float m2  = acc01.y;
                const float sPP = acc23.x;      // E[p^2]+E[t^2]
                const float e12 = acc23.y;      // E[p*t]
                const float m1m2 = m1 * m2;
                const float msq  = fmaf(m1, m1, m2 * m2);
                const float num = fmaf(2.0f, m1m2, C1f) * fmaf(2.0f, (e12 - m1m2), C2f);
                const float den = (msq + C1f) * ((sPP - msq) + C2f);
                lsum = fmaf(num, __builtin_amdgcn_rcpf(den), lsum);
            }
        }
    }

    // ---------------- Reduction: wave shuffle -> LDS -> plain store --------
    #pragma unroll
    for (int off = 32; off > 0; off >>= 1) lsum += __shfl_down(lsum, off, 64);
    const int lane = tid & 63;
    const int wv   = tid >> 6;              // 0..4
    if (lane == 0) wsum[wv] = lsum;
    __syncthreads();
    if (tid == 0) {
        ws[b] = wsum[0] + wsum[1] + wsum[2] + wsum[3] + wsum[4];
    }
}

extern "C" void kernel_launch(void* const* d_in, const int* in_sizes, int n_in,
                              void* d_out, int out_size, void* d_ws, size_t ws_size,
                              hipStream_t stream) {
    const float* pred = (const float*)d_in[0];
    const float* targ = (const float*)d_in[1];
    float* out = (float*)d_out;
    float* wsf = (float*)d_ws;               // needs 12288 floats = 48 KB

    hipLaunchKernelGGL(ssim_main, dim3(NBLK), dim3(NTHR), 0, stream,
                       pred, targ, wsf);
    hipLaunchKernelGGL(ssim_reduce, dim3(1), dim3(1024), 0, stream, wsf, out);
}

// Round 17
// 78.757 us; speedup vs baseline: 2.5216x; 1.0916x over previous
//
#include <hip/hip_runtime.h>

// SSIM loss, fused separable Gaussian (11x11, sigma=1.5) over [32,3,512,512] f32.
// R17 = R16 with 512-thread blocks (8 waves), same 8x256 tile, same LDS:
//  - V-phase unchanged (tid<266, 18-row column FIR, batch loads, uniform
//    border branch at ht==0/63).
//  - H-phase now uses ALL 512 threads: 8 rows x 64 lanes, ONE row-quad per
//    thread (was: 256 threads x two quads + 64 idle). Per-block critical
//    path = V + 1xH_quad (was V + 2xH_quad), ~-20%.
//  - LDS/block unchanged (34.8 KB -> 4 blocks/CU) but waves/CU cap rises
//    20 -> 32: pure balance + residency win, instruction count identical.
// Kept: independent one-tile blocks, XCD-bijective swizzle, pk f32x2 chains,
// linear stats LDS (32B-stride H reads, known ~4-way), plain store + reduce.

typedef float f32x2 __attribute__((ext_vector_type(2)));

#define IH 512
#define IW 512
#define TH 8                 // output rows per tile
#define TW 256               // output cols per tile
#define PW 266               // TW + 10 FIR cols
#define RRN 18               // raw rows per tile
#define LPW 268              // stats row stride in f32x2
#define HTILES 64
#define NBLK 12288           // 96 images * 64 ht * 2 wt
#define CPX 1536             // NBLK / 8 XCDs (exact -> bijective)
#define NPIX 25165824.0f     // 96*512*512
#define NTHR 512

constexpr float GW[11] = {
    0.00102838f, 0.00759877f, 0.03600078f, 0.10936070f, 0.21300554f,
    0.26601173f,
    0.21300554f, 0.10936070f, 0.03600078f, 0.00759877f, 0.00102838f
};
constexpr float C1f = 0.0001f;  // 0.01^2
constexpr float C2f = 0.0009f;  // 0.03^2

__global__ __launch_bounds__(1024) void ssim_reduce(
    const float* __restrict__ ws, float* __restrict__ out)
{
    __shared__ float wsum[16];
    const int tid = threadIdx.x;
    const float4* w4 = reinterpret_cast<const float4*>(ws);  // 3072 float4
    float s = 0.0f;
    #pragma unroll
    for (int i = 0; i < 3; ++i) {
        const float4 v = w4[tid + i * 1024];
        s += (v.x + v.y) + (v.z + v.w);
    }
    #pragma unroll
    for (int off = 32; off > 0; off >>= 1) s += __shfl_down(s, off, 64);
    if ((tid & 63) == 0) wsum[tid >> 6] = s;
    __syncthreads();
    if (tid == 0) {
        float t = 0.f;
        #pragma unroll
        for (int i = 0; i < 16; ++i) t += wsum[i];
        out[0] = 1.0f - t * (1.0f / NPIX);
    }
}

__global__ __launch_bounds__(NTHR, 8) void ssim_main(
    const float* __restrict__ pred,
    const float* __restrict__ targ,
    float* __restrict__ ws)
{
    __shared__ __align__(16) f32x2 lds01[TH][LPW];   // (E[p], E[t])
    __shared__ __align__(16) f32x2 lds23[TH][LPW];   // (E[p^2+t^2], E[p*t])
    __shared__ float wsum[8];

    const int tid = threadIdx.x;

    // -------- XCD-bijective swizzle: tl-consecutive tiles share an XCD -----
    const int b  = blockIdx.x;
    const int tl = (b & 7) * CPX + (b >> 3);
    const int ht = tl & (HTILES - 1);            // consecutive ht share rows
    const int wt = (tl >> 6) & 1;
    const int bc = tl >> 7;

    const int rbase = ht * TH - 5;
    const bool vint = (ht != 0) && (ht != HTILES - 1);   // uniform
    const float* __restrict__ P = pred + (size_t)bc * (IH * IW);
    const float* __restrict__ T = targ + (size_t)bc * (IH * IW);

    // ---------------- V-phase: 18-row column FIR (tid < 266) ---------------
    if (tid < PW) {
        const int w = wt * TW - 5 + tid;
        const float wm = ((unsigned)w < (unsigned)IW) ? 1.0f : 0.0f;
        const int wc = w < 0 ? 0 : (w > IW - 1 ? IW - 1 : w);

        float pv[RRN], tv[RRN];
        if (vint) {
            // interior: no clamps, no masks
            const float* __restrict__ Pp = P + (size_t)rbase * IW + wc;
            const float* __restrict__ Tp = T + (size_t)rbase * IW + wc;
            #pragma unroll
            for (int rr = 0; rr < RRN; ++rr) pv[rr] = Pp[(size_t)rr * IW];
            #pragma unroll
            for (int rr = 0; rr < RRN; ++rr) tv[rr] = Tp[(size_t)rr * IW];
        } else {
            // border: clamp rows + zero masks
            #pragma unroll
            for (int rr = 0; rr < RRN; ++rr) {
                const int h = rbase + rr;
                const int hc = h < 0 ? 0 : (h > IH - 1 ? IH - 1 : h);
                const float rmk = ((unsigned)h < (unsigned)IH) ? 1.0f : 0.0f;
                pv[rr] = P[(size_t)hc * IW + wc] * rmk;
                tv[rr] = T[(size_t)hc * IW + wc] * rmk;
            }
        }
        __builtin_amdgcn_sched_barrier(0);   // batch loads before FIR

        f32x2 a01[TH], a23[TH];
        #pragma unroll
        for (int ro = 0; ro < TH; ++ro) {
            a01[ro] = (f32x2){0.f, 0.f};
            a23[ro] = (f32x2){0.f, 0.f};
        }

        #pragma unroll
        for (int rr = 0; rr < RRN; ++rr) {
            const float p = pv[rr], t = tv[rr];
            f32x2 s01; s01.x = p; s01.y = t;
            f32x2 s23;
            s23.x = fmaf(p, p, t * t);        // p^2 + t^2
            s23.y = p * t;                    // p*t
            #pragma unroll
            for (int ro = 0; ro < TH; ++ro) {
                const int k = rr - ro;        // static after unroll
                if (k >= 0 && k < 11) {
                    const f32x2 g = {GW[k], GW[k]};
                    a01[ro] = __builtin_elementwise_fma(g, s01, a01[ro]);
                    a23[ro] = __builtin_elementwise_fma(g, s23, a23[ro]);
                }
            }
        }
        const f32x2 wmv = {wm, wm};
        #pragma unroll
        for (int ro = 0; ro < TH; ++ro) {
            lds01[ro][tid] = a01[ro] * wmv;
            lds23[ro][tid] = a23[ro] * wmv;
        }
    }
    __syncthreads();

    // ---------------- H-phase: ALL 512 threads, one row-quad each ----------
    float lsum = 0.0f;
    {
        const int r  = tid >> 6;            // 0..7 (one row per wave)
        const int c0 = (tid & 63) << 2;     // 0..252 (f32x2 elements)

        float4 u4[7], v4[7];
        const float4* b01 = reinterpret_cast<const float4*>(&lds01[r][c0]);
        const float4* b23 = reinterpret_cast<const float4*>(&lds23[r][c0]);
        #pragma unroll
        for (int q = 0; q < 7; ++q) { u4[q] = b01[q]; v4[q] = b23[q]; }
        const f32x2* x01 = reinterpret_cast<const f32x2*>(u4);   // 14 elems
        const f32x2* x23 = reinterpret_cast<const f32x2*>(v4);

        #pragma unroll
        for (int j = 0; j < 4; ++j) {
            f32x2 acc01 = {0.f, 0.f};
            f32x2 acc23 = {0.f, 0.f};
            #pragma unroll
            for (int k = 0; k < 11; ++k) {
                const f32x2 g = {GW[k], GW[k]};
                acc01 = __builtin_elementwise_fma(g, x01[j + k], acc01);
                acc23 = __builtin_elementwise_fma(g, x23[j + k], acc23);
            }
            const float m1  = acc01.x;
            const float m2  = acc01.y;
            const float sPP = acc23.x;      // E[p^2]+E[t^2]
            const float e12 = acc23.y;      // E[p*t]
            const float m1m2 = m1 * m2;
            const float msq  = fmaf(m1, m1, m2 * m2);
            const float num = fmaf(2.0f, m1m2, C1f) * fmaf(2.0f, (e12 - m1m2), C2f);
            const float den = (msq + C1f) * ((sPP - msq) + C2f);
            lsum = fmaf(num, __builtin_amdgcn_rcpf(den), lsum);
        }
    }

    // ---------------- Reduction: wave shuffle -> LDS -> plain store --------
    #pragma unroll
    for (int off = 32; off > 0; off >>= 1) lsum += __shfl_down(lsum, off, 64);
    const int lane = tid & 63;
    const int wv   = tid >> 6;              // 0..7
    if (lane == 0) wsum[wv] = lsum;
    __syncthreads();
    if (tid == 0) {
        float bs = 0.f;
        #pragma unroll
        for (int i = 0; i < 8; ++i) bs += wsum[i];
        ws[b] = bs;
    }
}

extern "C" void kernel_launch(void* const* d_in, const int* in_sizes, int n_in,
                              void* d_out, int out_size, void* d_ws, size_t ws_size,
                              hipStream_t stream) {
    const float* pred = (const float*)d_in[0];
    const float* targ = (const float*)d_in[1];
    float* out = (float*)d_out;
    float* wsf = (float*)d_ws;               // needs 12288 floats = 48 KB

    hipLaunchKernelGGL(ssim_main, dim3(NBLK), dim3(NTHR), 0, stream,
                       pred, targ, wsf);
    hipLaunchKernelGGL(ssim_reduce, dim3(1), dim3(1024), 0, stream, wsf, out);
}